// Round 1
// 3964.479 us; speedup vs baseline: 1.2265x; 1.2265x over previous
//
#include <hip/hip_runtime.h>

// Problem constants (from reference)
#define V_SZ 32000
#define D_   768
#define NL_  8
#define DI_  1536      // 2*D
#define DS_  16
#define DC_  4
#define DR_  48
#define B_   2
#define L_   512
#define NTOK 1024      // B*L
#define EPS_ 1e-5f

typedef unsigned short u16;
typedef __attribute__((ext_vector_type(8))) short bf16x8;   // 8 bf16 in 4 VGPRs
typedef __attribute__((ext_vector_type(4))) float f32x4;
typedef __attribute__((ext_vector_type(4))) unsigned int u32x4;

// ---------------------------------------------------------------- helpers
__device__ __forceinline__ float sigmoidf_(float x) { return 1.f / (1.f + __expf(-x)); }
__device__ __forceinline__ float siluf_(float x)    { return x * sigmoidf_(x); }
__device__ __forceinline__ float softplusf_(float x){ return fmaxf(x, 0.f) + log1pf(__expf(-fabsf(x))); }

// fp32 -> bf16 bits, round-to-nearest-even
__device__ __forceinline__ unsigned f2bf(float x) {
  unsigned u = __float_as_uint(x);
  return (u + 0x7fffu + ((u >> 16) & 1u)) >> 16;
}
__device__ __forceinline__ float bf2f(unsigned b) { return __uint_as_float(b << 16); }

// async global->LDS, 16B per lane; lds base must be wave-uniform
__device__ __forceinline__ void g2l16(const void* g, void* l) {
  __builtin_amdgcn_global_load_lds(
      (const __attribute__((address_space(1))) void*)(unsigned long long)g,
      (__attribute__((address_space(3))) void*)(unsigned)(unsigned long long)l,
      16, 0, 0);
}

__device__ __forceinline__ float block_reduce_sum_256(float v, float* sbuf) {
  int tid = threadIdx.x;
  #pragma unroll
  for (int off = 32; off; off >>= 1) v += __shfl_down(v, off, 64);
  __syncthreads();
  if ((tid & 63) == 0) sbuf[tid >> 6] = v;
  __syncthreads();
  return sbuf[0] + sbuf[1] + sbuf[2] + sbuf[3];
}

// ---------------------------------------------------------------- embedding gather
__global__ __launch_bounds__(192) void embed_kernel(
    const int* __restrict__ ids, const float* __restrict__ emb, float* __restrict__ h) {
  int token = blockIdx.x;
  int v = ids[token];
  float4 val = ((const float4*)(emb + (size_t)v * D_))[threadIdx.x];
  ((float4*)(h + (size_t)token * D_))[threadIdx.x] = val;
}

// ---------------------------------------------------------------- t-embedding (tiny MLP), grid = B*3
__global__ __launch_bounds__(256) void temb_kernel(
    const float* __restrict__ t, const float* __restrict__ tw1, const float* __restrict__ tb1,
    const float* __restrict__ tw2, const float* __restrict__ tb2, float* __restrict__ temb) {
  __shared__ float a[D_];
  int b = blockIdx.x / 3, chunk = blockIdx.x % 3;
  float tv = t[b];
  for (int i = threadIdx.x; i < D_; i += 256) a[i] = siluf_(tv * tw1[i] + tb1[i]);
  __syncthreads();
  int j = chunk * 256 + threadIdx.x;
  float acc = tb2[j];
  for (int d = 0; d < D_; d++) acc += a[d] * tw2[d * D_ + j];
  temb[b * D_ + j] = acc;
}

// ---------------------------------------------------------------- LayerNorm (+optional temb add)
// also emits bf16 hi/lo split planes of the output (MFMA GEMM A-operand)
__global__ __launch_bounds__(256) void ln_kernel(
    const float* __restrict__ hin, const float* __restrict__ temb,
    const float* __restrict__ g, const float* __restrict__ bt, float* __restrict__ out,
    u16* __restrict__ oh, u16* __restrict__ ol) {
  __shared__ float sbuf[4];
  int token = blockIdx.x, b = token >> 9, tid = threadIdx.x;
  float v[3];
  #pragma unroll
  for (int i = 0; i < 3; i++) {
    int c = tid + i * 256;
    float x = hin[(size_t)token * D_ + c];
    if (temb) x += temb[b * D_ + c];
    v[i] = x;
  }
  float mean = block_reduce_sum_256(v[0] + v[1] + v[2], sbuf) * (1.f / D_);
  float d0 = v[0] - mean, d1 = v[1] - mean, d2 = v[2] - mean;
  float var = block_reduce_sum_256(d0 * d0 + d1 * d1 + d2 * d2, sbuf) * (1.f / D_);
  float r = rsqrtf(var + EPS_);
  #pragma unroll
  for (int i = 0; i < 3; i++) {
    int c = tid + i * 256;
    float o = (v[i] - mean) * r * g[c] + bt[c];
    size_t idx = (size_t)token * D_ + c;
    out[idx] = o;
    unsigned hb = f2bf(o);
    oh[idx] = (u16)hb;
    ol[idx] = (u16)f2bf(o - bf2f(hb));
  }
}

// ---------------------------------------------------------------- weight transpose + split
// W [K][Nfull] fp32, cols [n0, n0+64*gridDim.x) -> Bh/Bl [ncols][K] bf16 planes
__global__ __launch_bounds__(256) void wsplit_kernel(
    const float* __restrict__ W, int Nfull, int n0, int K,
    u16* __restrict__ Bh, u16* __restrict__ Bl) {
  __shared__ float t[64][65];
  const int k0 = blockIdx.y * 64, nl0 = blockIdx.x * 64;
  const int tid = threadIdx.x;
  for (int i = tid; i < 64 * 16; i += 256) {
    int kk = i >> 4, c4 = (i & 15) * 4;
    const float4 v = *(const float4*)(W + (size_t)(k0 + kk) * Nfull + n0 + nl0 + c4);
    t[kk][c4] = v.x; t[kk][c4 + 1] = v.y; t[kk][c4 + 2] = v.z; t[kk][c4 + 3] = v.w;
  }
  __syncthreads();
  const int n = tid >> 2, kc = (tid & 3) * 16;
  u16 hs[16] __attribute__((aligned(16)));
  u16 ls[16] __attribute__((aligned(16)));
  #pragma unroll
  for (int j = 0; j < 16; j++) {
    float v = t[kc + j][n];
    unsigned hb = f2bf(v);
    hs[j] = (u16)hb;
    ls[j] = (u16)f2bf(v - bf2f(hb));
  }
  size_t off = (size_t)(nl0 + n) * K + k0 + kc;
  *(u32x4*)(Bh + off)     = *(const u32x4*)hs;
  *(u32x4*)(Bh + off + 8) = *(const u32x4*)(hs + 8);
  *(u32x4*)(Bl + off)     = *(const u32x4*)ls;
  *(u32x4*)(Bl + off + 8) = *(const u32x4*)(ls + 8);
}

// ---------------------------------------------------------------- split-bf16x3 MFMA GEMM
// C[M,N] = (Ah+Al)[M,K] @ (Bh+Bl)^T[N,K] (+bias)(+res), fp32 out, ldc stride.
// A/B planes are [rows][K] bf16, K%32==0. Grid (M/BM, N/BN), nwg%8==0.
// LDS layout per plane: [row][4 k-slots of 16B], slot XOR-swizzled by ((row>>1)&3).
template <int BM, int BN>
__global__ __launch_bounds__(256) void gemm3(
    int K, int ldc,
    const u16* __restrict__ Ah, const u16* __restrict__ Al,
    const u16* __restrict__ Bh, const u16* __restrict__ Bl,
    const float* __restrict__ bias, const float* __restrict__ res,
    float* __restrict__ C) {
  constexpr int FM = BM / 32, FN = BN / 32;      // 16x16 frags per wave (2x2 wave grid)
  constexpr int CA = BM / 16, CB = BN / 16;      // 16-row staging chunks per plane
  constexpr int TOT = 2 * (CA + CB), CPW = TOT / 4;
  __shared__ __attribute__((aligned(16))) u16 lds[(2 * BM + 2 * BN) * 32];
  u16* const Ahs = lds;
  u16* const Als = lds + BM * 32;
  u16* const Bhs = lds + 2 * BM * 32;
  u16* const Bls = lds + 2 * BM * 32 + BN * 32;

  // bijective XCD swizzle: consecutive same-XCD blocks sweep all m for one n-panel
  const int nwgx = gridDim.x;
  const int nwg = nwgx * gridDim.y;
  int lin = blockIdx.y * nwgx + blockIdx.x;
  int swz = (lin & 7) * (nwg >> 3) + (lin >> 3);
  const int m0 = (swz % nwgx) * BM;
  const int n0 = (swz / nwgx) * BN;

  const int tid = threadIdx.x, wave = tid >> 6, lane = tid & 63;
  const int wm = wave >> 1, wn = wave & 1;
  const int lr = lane & 15, q = lane >> 4;
  const int rl = lane >> 2, sl0 = lane & 3;

  f32x4 acc[FM][FN] = {};

  for (int k0 = 0; k0 < K; k0 += 32) {
    __syncthreads();                             // prev compute done before overwrite
    #pragma unroll
    for (int j = 0; j < CPW; j++) {
      int c = wave * CPW + j;
      int p, cl, gr0;
      if (c < CA)               { p = 0; cl = c;               gr0 = m0; }
      else if (c < 2 * CA)      { p = 1; cl = c - CA;          gr0 = m0; }
      else if (c < 2 * CA + CB) { p = 2; cl = c - 2 * CA;      gr0 = n0; }
      else                      { p = 3; cl = c - 2 * CA - CB; gr0 = n0; }
      const u16* gp = (p == 0) ? Ah : (p == 1) ? Al : (p == 2) ? Bh : Bl;
      u16* lp       = (p == 0) ? Ahs : (p == 1) ? Als : (p == 2) ? Bhs : Bls;
      int r = cl * 16 + rl;                      // plane-local row
      int s = sl0 ^ ((r >> 1) & 3);              // pre-swizzled source slot
      const u16* src = gp + (size_t)(gr0 + r) * K + k0 + s * 8;
      g2l16(src, lp + cl * 512);                 // wave-uniform LDS base, linear dest
    }
    __syncthreads();                             // compiler drains vmcnt before barrier

    bf16x8 a0[FM], a1[FM], b0[FN], b1[FN];
    #pragma unroll
    for (int i = 0; i < FM; i++) {
      int r = wm * (BM / 2) + i * 16 + lr;
      int s = q ^ ((r >> 1) & 3);
      a0[i] = *(const bf16x8*)(Ahs + r * 32 + s * 8);
      a1[i] = *(const bf16x8*)(Als + r * 32 + s * 8);
    }
    #pragma unroll
    for (int jn = 0; jn < FN; jn++) {
      int r = wn * (BN / 2) + jn * 16 + lr;
      int s = q ^ ((r >> 1) & 3);
      b0[jn] = *(const bf16x8*)(Bhs + r * 32 + s * 8);
      b1[jn] = *(const bf16x8*)(Bls + r * 32 + s * 8);
    }
    #pragma unroll
    for (int i = 0; i < FM; i++)
      #pragma unroll
      for (int jn = 0; jn < FN; jn++) {
        acc[i][jn] = __builtin_amdgcn_mfma_f32_16x16x32_bf16(a0[i], b0[jn], acc[i][jn], 0, 0, 0);
        acc[i][jn] = __builtin_amdgcn_mfma_f32_16x16x32_bf16(a1[i], b0[jn], acc[i][jn], 0, 0, 0);
        acc[i][jn] = __builtin_amdgcn_mfma_f32_16x16x32_bf16(a0[i], b1[jn], acc[i][jn], 0, 0, 0);
      }
  }

  // epilogue: C/D layout col=lane&15, row=(lane>>4)*4+reg (HW-verified mapping)
  #pragma unroll
  for (int i = 0; i < FM; i++) {
    int mbase = m0 + wm * (BM / 2) + i * 16 + q * 4;
    #pragma unroll
    for (int jn = 0; jn < FN; jn++) {
      int n = n0 + wn * (BN / 2) + jn * 16 + lr;
      float bv = bias ? bias[n] : 0.f;
      #pragma unroll
      for (int r2 = 0; r2 < 4; r2++) {
        size_t off = (size_t)(mbase + r2) * ldc + n;
        float o = acc[i][jn][r2] + bv;
        if (res) o += res[off];
        C[off] = o;
      }
    }
  }
}

// ---------------------------------------------------------------- depthwise causal conv(4) + silu
__global__ __launch_bounds__(256) void conv_silu_kernel(
    const float* __restrict__ xz, const float* __restrict__ cw,
    const float* __restrict__ cb, float* __restrict__ xc) {
  int i = blockIdx.x * 256 + threadIdx.x;
  int d = i % DI_;
  int tk = i / DI_;
  int t = tk & (L_ - 1);
  float acc = cb[d];
  #pragma unroll
  for (int k = 0; k < DC_; k++) {
    int tt = t - 3 + k;
    if (tt >= 0) acc += xz[(size_t)(tk - 3 + k) * (2 * DI_) + d] * cw[d * DC_ + k];
  }
  xc[i] = siluf_(acc);
}

// ---------------------------------------------------------------- xdbl = xc @ W_x  (N=80, K=1536)
__global__ __launch_bounds__(640) void xdbl_kernel(
    const float* __restrict__ xc, const float* __restrict__ Wx, float* __restrict__ xdbl) {
  __shared__ float As[8][DI_];
  int m0 = blockIdx.x * 8;
  for (int i = threadIdx.x; i < 8 * DI_; i += 640)
    As[i / DI_][i % DI_] = xc[(size_t)(m0 + i / DI_) * DI_ + (i % DI_)];
  __syncthreads();
  int r = threadIdx.x / 80, n = threadIdx.x % 80;
  float acc = 0.f;
  for (int k = 0; k < DI_; k++) acc += As[r][k] * Wx[k * 80 + n];
  xdbl[(size_t)(m0 + r) * 80 + n] = acc;
}

// ---------------------------------------------------------------- dt = softplus(xdbl[:, :48] @ W_dt + b_dt)
__global__ __launch_bounds__(256) void dt_kernel(
    const float* __restrict__ xdbl, const float* __restrict__ Wdt,
    const float* __restrict__ bdt, float* __restrict__ dt) {
  __shared__ float As[4][DR_];
  int m0 = blockIdx.x * 4;
  for (int i = threadIdx.x; i < 4 * DR_; i += 256)
    As[i / DR_][i % DR_] = xdbl[(size_t)(m0 + i / DR_) * 80 + (i % DR_)];
  __syncthreads();
  for (int j = 0; j < DI_ / 256; j++) {
    int n = j * 256 + threadIdx.x;
    float bv0 = bdt[n];
    float a0 = bv0, a1 = bv0, a2 = bv0, a3 = bv0;
    for (int k = 0; k < DR_; k++) {
      float bv = Wdt[k * DI_ + n];
      a0 += As[0][k] * bv; a1 += As[1][k] * bv; a2 += As[2][k] * bv; a3 += As[3][k] * bv;
    }
    dt[(size_t)(m0 + 0) * DI_ + n] = softplusf_(a0);
    dt[(size_t)(m0 + 1) * DI_ + n] = softplusf_(a1);
    dt[(size_t)(m0 + 2) * DI_ + n] = softplusf_(a2);
    dt[(size_t)(m0 + 3) * DI_ + n] = softplusf_(a3);
  }
}

// ---------------------------------------------------------------- selective scan
// grid = B * (DI/16) = 192 blocks; block = 256 = 16 channels x 16 states
// output: y split into bf16 hi/lo planes (W_out GEMM A-operand)
#define LCHUNK 64
__global__ __launch_bounds__(256) void scan_kernel(
    const float* __restrict__ dt,
    const float* __restrict__ xc,
    const float* __restrict__ xdbl,
    const float* __restrict__ xz,
    const float* __restrict__ A_log,
    const float* __restrict__ Dp,
    u16* __restrict__ yh, u16* __restrict__ yl) {
  __shared__ float dts[LCHUNK][16], xs[LCHUNK][16], zs[LCHUNK][16];
  __shared__ float Bs[LCHUNK][16], Cs[LCHUNK][16], ys[LCHUNK][16];
  int blk = blockIdx.x;
  int b = blk / (DI_ / 16);
  int dbase = (blk % (DI_ / 16)) * 16;
  int tid = threadIdx.x;
  int ch = tid >> 4;
  int st = tid & 15;
  int d = dbase + ch;
  float Av  = -__expf(A_log[d * DS_ + st]);
  float Dpd = Dp[d];
  float s = 0.f;
  int tok0 = b * L_;
  for (int c0 = 0; c0 < L_; c0 += LCHUNK) {
    #pragma unroll
    for (int rep = 0; rep < LCHUNK / 16; rep++) {
      int tt = rep * 16 + (tid >> 4);
      int cc = tid & 15;
      int tok = tok0 + c0 + tt;
      dts[tt][cc] = dt[(size_t)tok * DI_ + dbase + cc];
      xs [tt][cc] = xc[(size_t)tok * DI_ + dbase + cc];
      zs [tt][cc] = xz[(size_t)tok * (2 * DI_) + DI_ + dbase + cc];
      Bs [tt][cc] = xdbl[(size_t)tok * 80 + 48 + cc];
      Cs [tt][cc] = xdbl[(size_t)tok * 80 + 64 + cc];
    }
    __syncthreads();
    for (int tt = 0; tt < LCHUNK; tt++) {
      float dtv = dts[tt][ch];
      float xv  = xs[tt][ch];
      float e = __expf(dtv * Av);
      s = s * e + dtv * xv * Bs[tt][st];
      float p = s * Cs[tt][st];
      p += __shfl_xor(p, 1, 64);
      p += __shfl_xor(p, 2, 64);
      p += __shfl_xor(p, 4, 64);
      p += __shfl_xor(p, 8, 64);
      if (st == 0) {
        float yv = p + Dpd * xv;
        float zv = zs[tt][ch];
        ys[tt][ch] = yv * siluf_(zv);
      }
    }
    __syncthreads();
    #pragma unroll
    for (int rep = 0; rep < LCHUNK / 16; rep++) {
      int tt = rep * 16 + (tid >> 4);
      int cc = tid & 15;
      int tok = tok0 + c0 + tt;
      float v = ys[tt][cc];
      unsigned hb = f2bf(v);
      size_t idx = (size_t)tok * DI_ + dbase + cc;
      yh[idx] = (u16)hb;
      yl[idx] = (u16)f2bf(v - bf2f(hb));
    }
    __syncthreads();
  }
}

// ---------------------------------------------------------------- launcher
extern "C" void kernel_launch(void* const* d_in, const int* in_sizes, int n_in,
                              void* d_out, int out_size, void* d_ws, size_t ws_size,
                              hipStream_t stream) {
  const int*   ids     = (const int*)  d_in[0];
  const float* t_norm  = (const float*)d_in[1];
  const float* tok_emb = (const float*)d_in[2];
  const float* tw1     = (const float*)d_in[3];
  const float* tb1     = (const float*)d_in[4];
  const float* tw2     = (const float*)d_in[5];
  const float* tb2     = (const float*)d_in[6];
  const float* ln_g    = (const float*)d_in[7];
  const float* ln_b    = (const float*)d_in[8];
  const float* W_in    = (const float*)d_in[9];
  const float* b_in    = (const float*)d_in[10];
  const float* conv_w  = (const float*)d_in[11];
  const float* conv_b  = (const float*)d_in[12];
  const float* W_x     = (const float*)d_in[13];
  const float* W_dt    = (const float*)d_in[14];
  const float* b_dt    = (const float*)d_in[15];
  const float* A_log   = (const float*)d_in[16];
  const float* D_p     = (const float*)d_in[17];
  const float* W_out   = (const float*)d_in[18];
  const float* b_out   = (const float*)d_in[19];
  const float* fn_g    = (const float*)d_in[20];
  const float* fn_b    = (const float*)d_in[21];
  const float* W_head  = (const float*)d_in[22];
  const float* b_head  = (const float*)d_in[23];

  float* ws = (float*)d_ws;
  float* h    = ws; ws += (size_t)NTOK * D_;
  float* hn   = ws; ws += (size_t)NTOK * D_;
  float* temb = ws; ws += (size_t)B_ * D_;
  float* xz   = ws; ws += (size_t)NTOK * 2 * DI_;
  float* xc   = ws; ws += (size_t)NTOK * DI_;
  float* dtb  = ws; ws += (size_t)NTOK * DI_;
  float* xdbl = ws; ws += (size_t)NTOK * 80;
  u16* hnh = (u16*)ws; ws += (size_t)NTOK * D_ / 2;
  u16* hnl = (u16*)ws; ws += (size_t)NTOK * D_ / 2;
  u16* yh  = (u16*)ws; ws += (size_t)NTOK * DI_ / 2;
  u16* yl  = (u16*)ws; ws += (size_t)NTOK * DI_ / 2;
  u16* wbh = (u16*)ws; ws += (size_t)6400 * 768 / 2;   // weight split buffer (reused)
  u16* wbl = (u16*)ws; ws += (size_t)6400 * 768 / 2;

  embed_kernel<<<NTOK, 192, 0, stream>>>(ids, tok_emb, h);
  temb_kernel<<<B_ * 3, 256, 0, stream>>>(t_norm, tw1, tb1, tw2, tb2, temb);

  for (int l = 0; l < NL_; l++) {
    // W_in [768][3072] -> [3072][768] split planes
    wsplit_kernel<<<dim3(3072 / 64, 768 / 64), 256, 0, stream>>>(
        W_in + (size_t)l * D_ * 2 * DI_, 3072, 0, 768, wbh, wbl);
    ln_kernel<<<NTOK, 256, 0, stream>>>(h, temb, ln_g + l * D_, ln_b + l * D_, hn, hnh, hnl);
    // xz = hn @ W_in + b_in   (M=1024, N=3072, K=768)
    gemm3<128, 64><<<dim3(NTOK / 128, 3072 / 64), 256, 0, stream>>>(
        768, 3072, hnh, hnl, wbh, wbl, b_in + (size_t)l * 2 * DI_, nullptr, xz);
    conv_silu_kernel<<<(NTOK * DI_) / 256, 256, 0, stream>>>(
        xz, conv_w + (size_t)l * DI_ * DC_, conv_b + (size_t)l * DI_, xc);
    xdbl_kernel<<<NTOK / 8, 640, 0, stream>>>(xc, W_x + (size_t)l * DI_ * 80, xdbl);
    dt_kernel<<<NTOK / 4, 256, 0, stream>>>(
        xdbl, W_dt + (size_t)l * DR_ * DI_, b_dt + (size_t)l * DI_, dtb);
    scan_kernel<<<B_ * (DI_ / 16), 256, 0, stream>>>(
        dtb, xc, xdbl, xz, A_log + (size_t)l * DI_ * DS_, D_p + (size_t)l * DI_, yh, yl);
    // W_out [1536][768] -> [768][1536] split planes
    wsplit_kernel<<<dim3(768 / 64, 1536 / 64), 256, 0, stream>>>(
        W_out + (size_t)l * DI_ * D_, 768, 0, 1536, wbh, wbl);
    // h = hn + y @ W_out + b_out   (M=1024, N=768, K=1536; res = hn)
    gemm3<64, 64><<<dim3(NTOK / 64, D_ / 64), 256, 0, stream>>>(
        1536, 768, yh, yl, wbh, wbl, b_out + (size_t)l * D_, hn, h);
  }

  ln_kernel<<<NTOK, 256, 0, stream>>>(h, nullptr, fn_g, fn_b, hn, hnh, hnl);
  // head in 5 chunks of 6400 columns: split W_head slice, then GEMM
  for (int c = 0; c < 5; c++) {
    int c0 = c * 6400;
    wsplit_kernel<<<dim3(6400 / 64, 768 / 64), 256, 0, stream>>>(
        W_head, V_SZ, c0, 768, wbh, wbl);
    gemm3<128, 64><<<dim3(NTOK / 128, 6400 / 64), 256, 0, stream>>>(
        768, V_SZ, hnh, hnl, wbh, wbl, b_head + c0, nullptr, (float*)d_out + c0);
  }
}

// Round 2
// 3209.410 us; speedup vs baseline: 1.5151x; 1.2353x over previous
//
#include <hip/hip_runtime.h>

// Problem constants (from reference)
#define V_SZ 32000
#define D_   768
#define NL_  8
#define DI_  1536      // 2*D
#define DS_  16
#define DC_  4
#define DR_  48
#define B_   2
#define L_   512
#define NTOK 1024      // B*L
#define EPS_ 1e-5f

// chunked scan
#define NCH 8
#define TCH (L_ / NCH)   // 64

typedef unsigned short u16;
typedef __attribute__((ext_vector_type(8))) short bf16x8;   // 8 bf16 in 4 VGPRs
typedef __attribute__((ext_vector_type(4))) float f32x4;
typedef __attribute__((ext_vector_type(4))) unsigned int u32x4;

// ---------------------------------------------------------------- helpers
__device__ __forceinline__ float sigmoidf_(float x) { return 1.f / (1.f + __expf(-x)); }
__device__ __forceinline__ float siluf_(float x)    { return x * sigmoidf_(x); }
__device__ __forceinline__ float softplusf_(float x){ return fmaxf(x, 0.f) + log1pf(__expf(-fabsf(x))); }

// fp32 -> bf16 bits, round-to-nearest-even
__device__ __forceinline__ unsigned f2bf(float x) {
  unsigned u = __float_as_uint(x);
  return (u + 0x7fffu + ((u >> 16) & 1u)) >> 16;
}
__device__ __forceinline__ float bf2f(unsigned b) { return __uint_as_float(b << 16); }

// async global->LDS, 16B per lane; lds base must be wave-uniform
__device__ __forceinline__ void g2l16(const void* g, void* l) {
  __builtin_amdgcn_global_load_lds(
      (const __attribute__((address_space(1))) void*)(unsigned long long)g,
      (__attribute__((address_space(3))) void*)(unsigned)(unsigned long long)l,
      16, 0, 0);
}

__device__ __forceinline__ float block_reduce_sum_256(float v, float* sbuf) {
  int tid = threadIdx.x;
  #pragma unroll
  for (int off = 32; off; off >>= 1) v += __shfl_down(v, off, 64);
  __syncthreads();
  if ((tid & 63) == 0) sbuf[tid >> 6] = v;
  __syncthreads();
  return sbuf[0] + sbuf[1] + sbuf[2] + sbuf[3];
}

// ---------------------------------------------------------------- embedding gather
__global__ __launch_bounds__(192) void embed_kernel(
    const int* __restrict__ ids, const float* __restrict__ emb, float* __restrict__ h) {
  int token = blockIdx.x;
  int v = ids[token];
  float4 val = ((const float4*)(emb + (size_t)v * D_))[threadIdx.x];
  ((float4*)(h + (size_t)token * D_))[threadIdx.x] = val;
}

// ---------------------------------------------------------------- t-embedding (tiny MLP), grid = B*3
__global__ __launch_bounds__(256) void temb_kernel(
    const float* __restrict__ t, const float* __restrict__ tw1, const float* __restrict__ tb1,
    const float* __restrict__ tw2, const float* __restrict__ tb2, float* __restrict__ temb) {
  __shared__ float a[D_];
  int b = blockIdx.x / 3, chunk = blockIdx.x % 3;
  float tv = t[b];
  for (int i = threadIdx.x; i < D_; i += 256) a[i] = siluf_(tv * tw1[i] + tb1[i]);
  __syncthreads();
  int j = chunk * 256 + threadIdx.x;
  float acc = tb2[j];
  for (int d = 0; d < D_; d++) acc += a[d] * tw2[d * D_ + j];
  temb[b * D_ + j] = acc;
}

// ---------------------------------------------------------------- LayerNorm (+optional temb add)
// also emits bf16 hi/lo split planes of the output (MFMA GEMM A-operand)
__global__ __launch_bounds__(256) void ln_kernel(
    const float* __restrict__ hin, const float* __restrict__ temb,
    const float* __restrict__ g, const float* __restrict__ bt, float* __restrict__ out,
    u16* __restrict__ oh, u16* __restrict__ ol) {
  __shared__ float sbuf[4];
  int token = blockIdx.x, b = token >> 9, tid = threadIdx.x;
  float v[3];
  #pragma unroll
  for (int i = 0; i < 3; i++) {
    int c = tid + i * 256;
    float x = hin[(size_t)token * D_ + c];
    if (temb) x += temb[b * D_ + c];
    v[i] = x;
  }
  float mean = block_reduce_sum_256(v[0] + v[1] + v[2], sbuf) * (1.f / D_);
  float d0 = v[0] - mean, d1 = v[1] - mean, d2 = v[2] - mean;
  float var = block_reduce_sum_256(d0 * d0 + d1 * d1 + d2 * d2, sbuf) * (1.f / D_);
  float r = rsqrtf(var + EPS_);
  #pragma unroll
  for (int i = 0; i < 3; i++) {
    int c = tid + i * 256;
    float o = (v[i] - mean) * r * g[c] + bt[c];
    size_t idx = (size_t)token * D_ + c;
    out[idx] = o;
    unsigned hb = f2bf(o);
    oh[idx] = (u16)hb;
    ol[idx] = (u16)f2bf(o - bf2f(hb));
  }
}

// ---------------------------------------------------------------- weight transpose + split
// W [K][Nfull] fp32, cols [n0, n0+64*gridDim.x) -> Bh/Bl [ncols][K] bf16 planes
__global__ __launch_bounds__(256) void wsplit_kernel(
    const float* __restrict__ W, int Nfull, int n0, int K,
    u16* __restrict__ Bh, u16* __restrict__ Bl) {
  __shared__ float t[64][65];
  const int k0 = blockIdx.y * 64, nl0 = blockIdx.x * 64;
  const int tid = threadIdx.x;
  for (int i = tid; i < 64 * 16; i += 256) {
    int kk = i >> 4, c4 = (i & 15) * 4;
    const float4 v = *(const float4*)(W + (size_t)(k0 + kk) * Nfull + n0 + nl0 + c4);
    t[kk][c4] = v.x; t[kk][c4 + 1] = v.y; t[kk][c4 + 2] = v.z; t[kk][c4 + 3] = v.w;
  }
  __syncthreads();
  const int n = tid >> 2, kc = (tid & 3) * 16;
  u16 hs[16] __attribute__((aligned(16)));
  u16 ls[16] __attribute__((aligned(16)));
  #pragma unroll
  for (int j = 0; j < 16; j++) {
    float v = t[kc + j][n];
    unsigned hb = f2bf(v);
    hs[j] = (u16)hb;
    ls[j] = (u16)f2bf(v - bf2f(hb));
  }
  size_t off = (size_t)(nl0 + n) * K + k0 + kc;
  *(u32x4*)(Bh + off)     = *(const u32x4*)hs;
  *(u32x4*)(Bh + off + 8) = *(const u32x4*)(hs + 8);
  *(u32x4*)(Bl + off)     = *(const u32x4*)ls;
  *(u32x4*)(Bl + off + 8) = *(const u32x4*)(ls + 8);
}

// ---------------------------------------------------------------- split-bf16x3 MFMA GEMM
// C[M,N] = (Ah+Al)[M,K] @ (Bh+Bl)^T[N,K] (+bias)(+res), fp32 out, ldc stride.
// A/B planes are [rows][K] bf16, K%32==0. Grid (M/BM, N/BN), nwg%8==0.
// LDS layout per plane: [row][4 k-slots of 16B], slot XOR-swizzled by ((row>>1)&3).
template <int BM, int BN>
__global__ __launch_bounds__(256) void gemm3(
    int K, int ldc,
    const u16* __restrict__ Ah, const u16* __restrict__ Al,
    const u16* __restrict__ Bh, const u16* __restrict__ Bl,
    const float* __restrict__ bias, const float* __restrict__ res,
    float* __restrict__ C) {
  constexpr int FM = BM / 32, FN = BN / 32;      // 16x16 frags per wave (2x2 wave grid)
  constexpr int CA = BM / 16, CB = BN / 16;      // 16-row staging chunks per plane
  constexpr int TOT = 2 * (CA + CB), CPW = TOT / 4;
  __shared__ __attribute__((aligned(16))) u16 lds[(2 * BM + 2 * BN) * 32];
  u16* const Ahs = lds;
  u16* const Als = lds + BM * 32;
  u16* const Bhs = lds + 2 * BM * 32;
  u16* const Bls = lds + 2 * BM * 32 + BN * 32;

  // bijective XCD swizzle: consecutive same-XCD blocks sweep all m for one n-panel
  const int nwgx = gridDim.x;
  const int nwg = nwgx * gridDim.y;
  int lin = blockIdx.y * nwgx + blockIdx.x;
  int swz = (lin & 7) * (nwg >> 3) + (lin >> 3);
  const int m0 = (swz % nwgx) * BM;
  const int n0 = (swz / nwgx) * BN;

  const int tid = threadIdx.x, wave = tid >> 6, lane = tid & 63;
  const int wm = wave >> 1, wn = wave & 1;
  const int lr = lane & 15, q = lane >> 4;
  const int rl = lane >> 2, sl0 = lane & 3;

  f32x4 acc[FM][FN] = {};

  for (int k0 = 0; k0 < K; k0 += 32) {
    __syncthreads();                             // prev compute done before overwrite
    #pragma unroll
    for (int j = 0; j < CPW; j++) {
      int c = wave * CPW + j;
      int p, cl, gr0;
      if (c < CA)               { p = 0; cl = c;               gr0 = m0; }
      else if (c < 2 * CA)      { p = 1; cl = c - CA;          gr0 = m0; }
      else if (c < 2 * CA + CB) { p = 2; cl = c - 2 * CA;      gr0 = n0; }
      else                      { p = 3; cl = c - 2 * CA - CB; gr0 = n0; }
      const u16* gp = (p == 0) ? Ah : (p == 1) ? Al : (p == 2) ? Bh : Bl;
      u16* lp       = (p == 0) ? Ahs : (p == 1) ? Als : (p == 2) ? Bhs : Bls;
      int r = cl * 16 + rl;                      // plane-local row
      int s = sl0 ^ ((r >> 1) & 3);              // pre-swizzled source slot
      const u16* src = gp + (size_t)(gr0 + r) * K + k0 + s * 8;
      g2l16(src, lp + cl * 512);                 // wave-uniform LDS base, linear dest
    }
    __syncthreads();                             // compiler drains vmcnt before barrier

    bf16x8 a0[FM], a1[FM], b0[FN], b1[FN];
    #pragma unroll
    for (int i = 0; i < FM; i++) {
      int r = wm * (BM / 2) + i * 16 + lr;
      int s = q ^ ((r >> 1) & 3);
      a0[i] = *(const bf16x8*)(Ahs + r * 32 + s * 8);
      a1[i] = *(const bf16x8*)(Als + r * 32 + s * 8);
    }
    #pragma unroll
    for (int jn = 0; jn < FN; jn++) {
      int r = wn * (BN / 2) + jn * 16 + lr;
      int s = q ^ ((r >> 1) & 3);
      b0[jn] = *(const bf16x8*)(Bhs + r * 32 + s * 8);
      b1[jn] = *(const bf16x8*)(Bls + r * 32 + s * 8);
    }
    #pragma unroll
    for (int i = 0; i < FM; i++)
      #pragma unroll
      for (int jn = 0; jn < FN; jn++) {
        acc[i][jn] = __builtin_amdgcn_mfma_f32_16x16x32_bf16(a0[i], b0[jn], acc[i][jn], 0, 0, 0);
        acc[i][jn] = __builtin_amdgcn_mfma_f32_16x16x32_bf16(a1[i], b0[jn], acc[i][jn], 0, 0, 0);
        acc[i][jn] = __builtin_amdgcn_mfma_f32_16x16x32_bf16(a0[i], b1[jn], acc[i][jn], 0, 0, 0);
      }
  }

  // epilogue: C/D layout col=lane&15, row=(lane>>4)*4+reg (HW-verified mapping)
  #pragma unroll
  for (int i = 0; i < FM; i++) {
    int mbase = m0 + wm * (BM / 2) + i * 16 + q * 4;
    #pragma unroll
    for (int jn = 0; jn < FN; jn++) {
      int n = n0 + wn * (BN / 2) + jn * 16 + lr;
      float bv = bias ? bias[n] : 0.f;
      #pragma unroll
      for (int r2 = 0; r2 < 4; r2++) {
        size_t off = (size_t)(mbase + r2) * ldc + n;
        float o = acc[i][jn][r2] + bv;
        if (res) o += res[off];
        C[off] = o;
      }
    }
  }
}

// ---------------------------------------------------------------- depthwise causal conv(4) + silu
__global__ __launch_bounds__(256) void conv_silu_kernel(
    const float* __restrict__ xz, const float* __restrict__ cw,
    const float* __restrict__ cb, float* __restrict__ xc) {
  int i = blockIdx.x * 256 + threadIdx.x;
  int d = i % DI_;
  int tk = i / DI_;
  int t = tk & (L_ - 1);
  float acc = cb[d];
  #pragma unroll
  for (int k = 0; k < DC_; k++) {
    int tt = t - 3 + k;
    if (tt >= 0) acc += xz[(size_t)(tk - 3 + k) * (2 * DI_) + d] * cw[d * DC_ + k];
  }
  xc[i] = siluf_(acc);
}

// ---------------------------------------------------------------- xdbl = xc @ W_x  (N=80, K=1536)
__global__ __launch_bounds__(640) void xdbl_kernel(
    const float* __restrict__ xc, const float* __restrict__ Wx, float* __restrict__ xdbl) {
  __shared__ float As[8][DI_];
  int m0 = blockIdx.x * 8;
  for (int i = threadIdx.x; i < 8 * DI_; i += 640)
    As[i / DI_][i % DI_] = xc[(size_t)(m0 + i / DI_) * DI_ + (i % DI_)];
  __syncthreads();
  int r = threadIdx.x / 80, n = threadIdx.x % 80;
  float acc = 0.f;
  for (int k = 0; k < DI_; k++) acc += As[r][k] * Wx[k * 80 + n];
  xdbl[(size_t)(m0 + r) * 80 + n] = acc;
}

// ---------------------------------------------------------------- dt = softplus(xdbl[:, :48] @ W_dt + b_dt)
__global__ __launch_bounds__(256) void dt_kernel(
    const float* __restrict__ xdbl, const float* __restrict__ Wdt,
    const float* __restrict__ bdt, float* __restrict__ dt) {
  __shared__ float As[4][DR_];
  int m0 = blockIdx.x * 4;
  for (int i = threadIdx.x; i < 4 * DR_; i += 256)
    As[i / DR_][i % DR_] = xdbl[(size_t)(m0 + i / DR_) * 80 + (i % DR_)];
  __syncthreads();
  for (int j = 0; j < DI_ / 256; j++) {
    int n = j * 256 + threadIdx.x;
    float bv0 = bdt[n];
    float a0 = bv0, a1 = bv0, a2 = bv0, a3 = bv0;
    for (int k = 0; k < DR_; k++) {
      float bv = Wdt[k * DI_ + n];
      a0 += As[0][k] * bv; a1 += As[1][k] * bv; a2 += As[2][k] * bv; a3 += As[3][k] * bv;
    }
    dt[(size_t)(m0 + 0) * DI_ + n] = softplusf_(a0);
    dt[(size_t)(m0 + 1) * DI_ + n] = softplusf_(a1);
    dt[(size_t)(m0 + 2) * DI_ + n] = softplusf_(a2);
    dt[(size_t)(m0 + 3) * DI_ + n] = softplusf_(a3);
  }
}

// ---------------------------------------------------------------- chunked selective scan
// Pass 1: per-chunk local scan summaries.
// grid = B * (DI/16) * NCH, block 256 = 16 channels x 16 states
__global__ __launch_bounds__(256) void scan1_kernel(
    const float* __restrict__ dt,
    const float* __restrict__ xc,
    const float* __restrict__ xdbl,
    const float* __restrict__ A_log,
    float* __restrict__ sumA, float* __restrict__ sumS) {
  __shared__ float dts[TCH][16], xs[TCH][16], Bs[TCH][16];
  int blk = blockIdx.x;
  int c = blk % NCH;
  int bd = blk / NCH;
  int b = bd / (DI_ / 16);
  int dbase = (bd % (DI_ / 16)) * 16;
  int tid = threadIdx.x;
  int ch = tid >> 4;
  int st = tid & 15;
  int d = dbase + ch;
  int tok0 = b * L_ + c * TCH;
  #pragma unroll
  for (int rep = 0; rep < TCH / 16; rep++) {
    int tt = rep * 16 + (tid >> 4);
    int cc = tid & 15;
    int tok = tok0 + tt;
    dts[tt][cc] = dt[(size_t)tok * DI_ + dbase + cc];
    xs [tt][cc] = xc[(size_t)tok * DI_ + dbase + cc];
    Bs [tt][cc] = xdbl[(size_t)tok * 80 + 48 + cc];
  }
  __syncthreads();
  float Av = -__expf(A_log[d * DS_ + st]);
  float s = 0.f, ap = 1.f;
  for (int tt = 0; tt < TCH; tt++) {
    float dtv = dts[tt][ch];
    float xv  = xs[tt][ch];
    float e = __expf(dtv * Av);
    s = s * e + dtv * xv * Bs[tt][st];
    ap *= e;
  }
  int idx = ((c * B_ + b) * DI_ + d) * DS_ + st;
  sumA[idx] = ap;
  sumS[idx] = s;
}

// Pass 2: combine chunk summaries -> carry-in per chunk. 49152 threads.
__global__ __launch_bounds__(256) void scan2_kernel(
    const float* __restrict__ sumA, const float* __restrict__ sumS,
    float* __restrict__ carry) {
  int i = blockIdx.x * 256 + threadIdx.x;
  const int stride = B_ * DI_ * DS_;
  float s = 0.f;
  #pragma unroll
  for (int c = 0; c < NCH; c++) {
    carry[c * stride + i] = s;
    s = sumS[c * stride + i] + sumA[c * stride + i] * s;
  }
}

// Pass 3: replay chunk with carry-in, compute y, emit bf16 hi/lo planes.
// grid = B * (DI/16) * NCH, block 256
__global__ __launch_bounds__(256) void scan3_kernel(
    const float* __restrict__ dt,
    const float* __restrict__ xc,
    const float* __restrict__ xdbl,
    const float* __restrict__ xz,
    const float* __restrict__ A_log,
    const float* __restrict__ Dp,
    const float* __restrict__ carry,
    u16* __restrict__ yh, u16* __restrict__ yl) {
  __shared__ float dts[TCH][16], xs[TCH][16], zs[TCH][16];
  __shared__ float Bs[TCH][16], Cs[TCH][16], ys[TCH][16];
  int blk = blockIdx.x;
  int c = blk % NCH;
  int bd = blk / NCH;
  int b = bd / (DI_ / 16);
  int dbase = (bd % (DI_ / 16)) * 16;
  int tid = threadIdx.x;
  int ch = tid >> 4;
  int st = tid & 15;
  int d = dbase + ch;
  int tok0 = b * L_ + c * TCH;
  #pragma unroll
  for (int rep = 0; rep < TCH / 16; rep++) {
    int tt = rep * 16 + (tid >> 4);
    int cc = tid & 15;
    int tok = tok0 + tt;
    dts[tt][cc] = dt[(size_t)tok * DI_ + dbase + cc];
    xs [tt][cc] = xc[(size_t)tok * DI_ + dbase + cc];
    zs [tt][cc] = xz[(size_t)tok * (2 * DI_) + DI_ + dbase + cc];
    Bs [tt][cc] = xdbl[(size_t)tok * 80 + 48 + cc];
    Cs [tt][cc] = xdbl[(size_t)tok * 80 + 64 + cc];
  }
  __syncthreads();
  float Av  = -__expf(A_log[d * DS_ + st]);
  float Dpd = Dp[d];
  float s = carry[((c * B_ + b) * DI_ + d) * DS_ + st];
  for (int tt = 0; tt < TCH; tt++) {
    float dtv = dts[tt][ch];
    float xv  = xs[tt][ch];
    float e = __expf(dtv * Av);
    s = s * e + dtv * xv * Bs[tt][st];
    float p = s * Cs[tt][st];
    p += __shfl_xor(p, 1, 64);
    p += __shfl_xor(p, 2, 64);
    p += __shfl_xor(p, 4, 64);
    p += __shfl_xor(p, 8, 64);
    if (st == 0) {
      float yv = p + Dpd * xv;
      float zv = zs[tt][ch];
      ys[tt][ch] = yv * siluf_(zv);
    }
  }
  __syncthreads();
  #pragma unroll
  for (int rep = 0; rep < TCH / 16; rep++) {
    int tt = rep * 16 + (tid >> 4);
    int cc = tid & 15;
    int tok = tok0 + tt;
    float v = ys[tt][cc];
    unsigned hb = f2bf(v);
    size_t idx = (size_t)tok * DI_ + dbase + cc;
    yh[idx] = (u16)hb;
    yl[idx] = (u16)f2bf(v - bf2f(hb));
  }
}

// ---------------------------------------------------------------- launcher
extern "C" void kernel_launch(void* const* d_in, const int* in_sizes, int n_in,
                              void* d_out, int out_size, void* d_ws, size_t ws_size,
                              hipStream_t stream) {
  const int*   ids     = (const int*)  d_in[0];
  const float* t_norm  = (const float*)d_in[1];
  const float* tok_emb = (const float*)d_in[2];
  const float* tw1     = (const float*)d_in[3];
  const float* tb1     = (const float*)d_in[4];
  const float* tw2     = (const float*)d_in[5];
  const float* tb2     = (const float*)d_in[6];
  const float* ln_g    = (const float*)d_in[7];
  const float* ln_b    = (const float*)d_in[8];
  const float* W_in    = (const float*)d_in[9];
  const float* b_in    = (const float*)d_in[10];
  const float* conv_w  = (const float*)d_in[11];
  const float* conv_b  = (const float*)d_in[12];
  const float* W_x     = (const float*)d_in[13];
  const float* W_dt    = (const float*)d_in[14];
  const float* b_dt    = (const float*)d_in[15];
  const float* A_log   = (const float*)d_in[16];
  const float* D_p     = (const float*)d_in[17];
  const float* W_out   = (const float*)d_in[18];
  const float* b_out   = (const float*)d_in[19];
  const float* fn_g    = (const float*)d_in[20];
  const float* fn_b    = (const float*)d_in[21];
  const float* W_head  = (const float*)d_in[22];
  const float* b_head  = (const float*)d_in[23];

  float* ws = (float*)d_ws;
  float* h    = ws; ws += (size_t)NTOK * D_;
  float* hn   = ws; ws += (size_t)NTOK * D_;
  float* temb = ws; ws += (size_t)B_ * D_;
  float* xz   = ws; ws += (size_t)NTOK * 2 * DI_;
  float* xc   = ws; ws += (size_t)NTOK * DI_;
  float* dtb  = ws; ws += (size_t)NTOK * DI_;
  float* xdbl = ws; ws += (size_t)NTOK * 80;
  u16* hnh = (u16*)ws; ws += (size_t)NTOK * D_ / 2;
  u16* hnl = (u16*)ws; ws += (size_t)NTOK * D_ / 2;
  u16* yh  = (u16*)ws; ws += (size_t)NTOK * DI_ / 2;
  u16* yl  = (u16*)ws; ws += (size_t)NTOK * DI_ / 2;
  u16* wbh = (u16*)ws; ws += (size_t)6400 * 768 / 2;   // weight split buffer (reused)
  u16* wbl = (u16*)ws; ws += (size_t)6400 * 768 / 2;
  float* sumA  = ws; ws += (size_t)NCH * B_ * DI_ * DS_;
  float* sumS  = ws; ws += (size_t)NCH * B_ * DI_ * DS_;
  float* carry = ws; ws += (size_t)NCH * B_ * DI_ * DS_;

  embed_kernel<<<NTOK, 192, 0, stream>>>(ids, tok_emb, h);
  temb_kernel<<<B_ * 3, 256, 0, stream>>>(t_norm, tw1, tb1, tw2, tb2, temb);

  for (int l = 0; l < NL_; l++) {
    // W_in [768][3072] -> [3072][768] split planes
    wsplit_kernel<<<dim3(3072 / 64, 768 / 64), 256, 0, stream>>>(
        W_in + (size_t)l * D_ * 2 * DI_, 3072, 0, 768, wbh, wbl);
    ln_kernel<<<NTOK, 256, 0, stream>>>(h, temb, ln_g + l * D_, ln_b + l * D_, hn, hnh, hnl);
    // xz = hn @ W_in + b_in   (M=1024, N=3072, K=768)
    gemm3<128, 64><<<dim3(NTOK / 128, 3072 / 64), 256, 0, stream>>>(
        768, 3072, hnh, hnl, wbh, wbl, b_in + (size_t)l * 2 * DI_, nullptr, xz);
    conv_silu_kernel<<<(NTOK * DI_) / 256, 256, 0, stream>>>(
        xz, conv_w + (size_t)l * DI_ * DC_, conv_b + (size_t)l * DI_, xc);
    xdbl_kernel<<<NTOK / 8, 640, 0, stream>>>(xc, W_x + (size_t)l * DI_ * 80, xdbl);
    dt_kernel<<<NTOK / 4, 256, 0, stream>>>(
        xdbl, W_dt + (size_t)l * DR_ * DI_, b_dt + (size_t)l * DI_, dtb);
    // chunked scan: local summaries -> carry combine -> replay+output
    scan1_kernel<<<B_ * (DI_ / 16) * NCH, 256, 0, stream>>>(
        dtb, xc, xdbl, A_log + (size_t)l * DI_ * DS_, sumA, sumS);
    scan2_kernel<<<(B_ * DI_ * DS_) / 256, 256, 0, stream>>>(sumA, sumS, carry);
    scan3_kernel<<<B_ * (DI_ / 16) * NCH, 256, 0, stream>>>(
        dtb, xc, xdbl, xz, A_log + (size_t)l * DI_ * DS_, D_p + (size_t)l * DI_, carry, yh, yl);
    // W_out [1536][768] -> [768][1536] split planes
    wsplit_kernel<<<dim3(768 / 64, 1536 / 64), 256, 0, stream>>>(
        W_out + (size_t)l * DI_ * D_, 768, 0, 1536, wbh, wbl);
    // h = hn + y @ W_out + b_out   (M=1024, N=768, K=1536; res = hn)
    gemm3<64, 64><<<dim3(NTOK / 64, D_ / 64), 256, 0, stream>>>(
        1536, 768, yh, yl, wbh, wbl, b_out + (size_t)l * D_, hn, h);
  }

  ln_kernel<<<NTOK, 256, 0, stream>>>(h, nullptr, fn_g, fn_b, hn, hnh, hnl);
  // head in 5 chunks of 6400 columns: split W_head slice, then GEMM
  for (int c = 0; c < 5; c++) {
    int c0 = c * 6400;
    wsplit_kernel<<<dim3(6400 / 64, 768 / 64), 256, 0, stream>>>(
        W_head, V_SZ, c0, 768, wbh, wbl);
    gemm3<128, 64><<<dim3(NTOK / 128, 6400 / 64), 256, 0, stream>>>(
        768, V_SZ, hnh, hnl, wbh, wbl, b_head + c0, nullptr, (float*)d_out + c0);
  }
}

// Round 3
// 2623.784 us; speedup vs baseline: 1.8533x; 1.2232x over previous
//
#include <hip/hip_runtime.h>

// Problem constants (from reference)
#define V_SZ 32000
#define D_   768
#define NL_  8
#define DI_  1536      // 2*D
#define DS_  16
#define DC_  4
#define DR_  48
#define B_   2
#define L_   512
#define NTOK 1024      // B*L
#define EPS_ 1e-5f

// chunked scan
#define NCH 8
#define TCH (L_ / NCH)   // 64

typedef unsigned short u16;
typedef __attribute__((ext_vector_type(8))) short bf16x8;   // 8 bf16 in 4 VGPRs
typedef __attribute__((ext_vector_type(4))) float f32x4;
typedef __attribute__((ext_vector_type(4))) unsigned int u32x4;

// ---------------------------------------------------------------- helpers
__device__ __forceinline__ float sigmoidf_(float x) { return 1.f / (1.f + __expf(-x)); }
__device__ __forceinline__ float siluf_(float x)    { return x * sigmoidf_(x); }
__device__ __forceinline__ float softplusf_(float x){ return fmaxf(x, 0.f) + log1pf(__expf(-fabsf(x))); }

// fp32 -> bf16 bits, round-to-nearest-even
__device__ __forceinline__ unsigned f2bf(float x) {
  unsigned u = __float_as_uint(x);
  return (u + 0x7fffu + ((u >> 16) & 1u)) >> 16;
}
__device__ __forceinline__ float bf2f(unsigned b) { return __uint_as_float(b << 16); }

// async global->LDS, 16B per lane; lds base must be wave-uniform
__device__ __forceinline__ void g2l16(const void* g, void* l) {
  __builtin_amdgcn_global_load_lds(
      (const __attribute__((address_space(1))) void*)(unsigned long long)g,
      (__attribute__((address_space(3))) void*)(unsigned)(unsigned long long)l,
      16, 0, 0);
}

__device__ __forceinline__ float block_reduce_sum_256(float v, float* sbuf) {
  int tid = threadIdx.x;
  #pragma unroll
  for (int off = 32; off; off >>= 1) v += __shfl_down(v, off, 64);
  __syncthreads();
  if ((tid & 63) == 0) sbuf[tid >> 6] = v;
  __syncthreads();
  return sbuf[0] + sbuf[1] + sbuf[2] + sbuf[3];
}

// ---------------------------------------------------------------- embedding gather
__global__ __launch_bounds__(192) void embed_kernel(
    const int* __restrict__ ids, const float* __restrict__ emb, float* __restrict__ h) {
  int token = blockIdx.x;
  int v = ids[token];
  float4 val = ((const float4*)(emb + (size_t)v * D_))[threadIdx.x];
  ((float4*)(h + (size_t)token * D_))[threadIdx.x] = val;
}

// ---------------------------------------------------------------- t-embedding (tiny MLP), grid = B*3
__global__ __launch_bounds__(256) void temb_kernel(
    const float* __restrict__ t, const float* __restrict__ tw1, const float* __restrict__ tb1,
    const float* __restrict__ tw2, const float* __restrict__ tb2, float* __restrict__ temb) {
  __shared__ float a[D_];
  int b = blockIdx.x / 3, chunk = blockIdx.x % 3;
  float tv = t[b];
  for (int i = threadIdx.x; i < D_; i += 256) a[i] = siluf_(tv * tw1[i] + tb1[i]);
  __syncthreads();
  int j = chunk * 256 + threadIdx.x;
  float acc = tb2[j];
  for (int d = 0; d < D_; d++) acc += a[d] * tw2[d * D_ + j];
  temb[b * D_ + j] = acc;
}

// ---------------------------------------------------------------- LayerNorm (+optional temb add)
// also emits bf16 hi/lo split planes of the output (MFMA GEMM A-operand)
__global__ __launch_bounds__(256) void ln_kernel(
    const float* __restrict__ hin, const float* __restrict__ temb,
    const float* __restrict__ g, const float* __restrict__ bt, float* __restrict__ out,
    u16* __restrict__ oh, u16* __restrict__ ol) {
  __shared__ float sbuf[4];
  int token = blockIdx.x, b = token >> 9, tid = threadIdx.x;
  float v[3];
  #pragma unroll
  for (int i = 0; i < 3; i++) {
    int c = tid + i * 256;
    float x = hin[(size_t)token * D_ + c];
    if (temb) x += temb[b * D_ + c];
    v[i] = x;
  }
  float mean = block_reduce_sum_256(v[0] + v[1] + v[2], sbuf) * (1.f / D_);
  float d0 = v[0] - mean, d1 = v[1] - mean, d2 = v[2] - mean;
  float var = block_reduce_sum_256(d0 * d0 + d1 * d1 + d2 * d2, sbuf) * (1.f / D_);
  float r = rsqrtf(var + EPS_);
  #pragma unroll
  for (int i = 0; i < 3; i++) {
    int c = tid + i * 256;
    float o = (v[i] - mean) * r * g[c] + bt[c];
    size_t idx = (size_t)token * D_ + c;
    out[idx] = o;
    unsigned hb = f2bf(o);
    oh[idx] = (u16)hb;
    ol[idx] = (u16)f2bf(o - bf2f(hb));
  }
}

// ---------------------------------------------------------------- weight transpose + split
// W [K][Nfull] fp32, cols [n0, n0+64*gridDim.x) -> Bh/Bl [ncols][K] bf16 planes
__global__ __launch_bounds__(256) void wsplit_kernel(
    const float* __restrict__ W, int Nfull, int n0, int K,
    u16* __restrict__ Bh, u16* __restrict__ Bl) {
  __shared__ float t[64][65];
  const int k0 = blockIdx.y * 64, nl0 = blockIdx.x * 64;
  const int tid = threadIdx.x;
  for (int i = tid; i < 64 * 16; i += 256) {
    int kk = i >> 4, c4 = (i & 15) * 4;
    const float4 v = *(const float4*)(W + (size_t)(k0 + kk) * Nfull + n0 + nl0 + c4);
    t[kk][c4] = v.x; t[kk][c4 + 1] = v.y; t[kk][c4 + 2] = v.z; t[kk][c4 + 3] = v.w;
  }
  __syncthreads();
  const int n = tid >> 2, kc = (tid & 3) * 16;
  u16 hs[16] __attribute__((aligned(16)));
  u16 ls[16] __attribute__((aligned(16)));
  #pragma unroll
  for (int j = 0; j < 16; j++) {
    float v = t[kc + j][n];
    unsigned hb = f2bf(v);
    hs[j] = (u16)hb;
    ls[j] = (u16)f2bf(v - bf2f(hb));
  }
  size_t off = (size_t)(nl0 + n) * K + k0 + kc;
  *(u32x4*)(Bh + off)     = *(const u32x4*)hs;
  *(u32x4*)(Bh + off + 8) = *(const u32x4*)(hs + 8);
  *(u32x4*)(Bl + off)     = *(const u32x4*)ls;
  *(u32x4*)(Bl + off + 8) = *(const u32x4*)(ls + 8);
}

// ---------------------------------------------------------------- split-bf16x3 MFMA GEMM
// C[M,N] = (Ah+Al)[M,K] @ (Bh+Bl)^T[N,K] (+bias)(+res), fp32 out, ldc stride.
// A/B planes are [rows][K] bf16, K%32==0. Grid (M/BM, N/BN), nwg%8==0.
// LDS layout per plane: [row][4 k-slots of 16B], slot XOR-swizzled by ((row>>1)&3).
template <int BM, int BN>
__global__ __launch_bounds__(256) void gemm3(
    int K, int ldc,
    const u16* __restrict__ Ah, const u16* __restrict__ Al,
    const u16* __restrict__ Bh, const u16* __restrict__ Bl,
    const float* __restrict__ bias, const float* __restrict__ res,
    float* __restrict__ C) {
  constexpr int FM = BM / 32, FN = BN / 32;      // 16x16 frags per wave (2x2 wave grid)
  constexpr int CA = BM / 16, CB = BN / 16;      // 16-row staging chunks per plane
  constexpr int TOT = 2 * (CA + CB), CPW = TOT / 4;
  __shared__ __attribute__((aligned(16))) u16 lds[(2 * BM + 2 * BN) * 32];
  u16* const Ahs = lds;
  u16* const Als = lds + BM * 32;
  u16* const Bhs = lds + 2 * BM * 32;
  u16* const Bls = lds + 2 * BM * 32 + BN * 32;

  // bijective XCD swizzle: consecutive same-XCD blocks sweep all m for one n-panel
  const int nwgx = gridDim.x;
  const int nwg = nwgx * gridDim.y;
  int lin = blockIdx.y * nwgx + blockIdx.x;
  int swz = (lin & 7) * (nwg >> 3) + (lin >> 3);
  const int m0 = (swz % nwgx) * BM;
  const int n0 = (swz / nwgx) * BN;

  const int tid = threadIdx.x, wave = tid >> 6, lane = tid & 63;
  const int wm = wave >> 1, wn = wave & 1;
  const int lr = lane & 15, q = lane >> 4;
  const int rl = lane >> 2, sl0 = lane & 3;

  f32x4 acc[FM][FN] = {};

  for (int k0 = 0; k0 < K; k0 += 32) {
    __syncthreads();                             // prev compute done before overwrite
    #pragma unroll
    for (int j = 0; j < CPW; j++) {
      int c = wave * CPW + j;
      int p, cl, gr0;
      if (c < CA)               { p = 0; cl = c;               gr0 = m0; }
      else if (c < 2 * CA)      { p = 1; cl = c - CA;          gr0 = m0; }
      else if (c < 2 * CA + CB) { p = 2; cl = c - 2 * CA;      gr0 = n0; }
      else                      { p = 3; cl = c - 2 * CA - CB; gr0 = n0; }
      const u16* gp = (p == 0) ? Ah : (p == 1) ? Al : (p == 2) ? Bh : Bl;
      u16* lp       = (p == 0) ? Ahs : (p == 1) ? Als : (p == 2) ? Bhs : Bls;
      int r = cl * 16 + rl;                      // plane-local row
      int s = sl0 ^ ((r >> 1) & 3);              // pre-swizzled source slot
      const u16* src = gp + (size_t)(gr0 + r) * K + k0 + s * 8;
      g2l16(src, lp + cl * 512);                 // wave-uniform LDS base, linear dest
    }
    __syncthreads();                             // compiler drains vmcnt before barrier

    bf16x8 a0[FM], a1[FM], b0[FN], b1[FN];
    #pragma unroll
    for (int i = 0; i < FM; i++) {
      int r = wm * (BM / 2) + i * 16 + lr;
      int s = q ^ ((r >> 1) & 3);
      a0[i] = *(const bf16x8*)(Ahs + r * 32 + s * 8);
      a1[i] = *(const bf16x8*)(Als + r * 32 + s * 8);
    }
    #pragma unroll
    for (int jn = 0; jn < FN; jn++) {
      int r = wn * (BN / 2) + jn * 16 + lr;
      int s = q ^ ((r >> 1) & 3);
      b0[jn] = *(const bf16x8*)(Bhs + r * 32 + s * 8);
      b1[jn] = *(const bf16x8*)(Bls + r * 32 + s * 8);
    }
    #pragma unroll
    for (int i = 0; i < FM; i++)
      #pragma unroll
      for (int jn = 0; jn < FN; jn++) {
        acc[i][jn] = __builtin_amdgcn_mfma_f32_16x16x32_bf16(a0[i], b0[jn], acc[i][jn], 0, 0, 0);
        acc[i][jn] = __builtin_amdgcn_mfma_f32_16x16x32_bf16(a1[i], b0[jn], acc[i][jn], 0, 0, 0);
        acc[i][jn] = __builtin_amdgcn_mfma_f32_16x16x32_bf16(a0[i], b1[jn], acc[i][jn], 0, 0, 0);
      }
  }

  // epilogue: C/D layout col=lane&15, row=(lane>>4)*4+reg (HW-verified mapping)
  #pragma unroll
  for (int i = 0; i < FM; i++) {
    int mbase = m0 + wm * (BM / 2) + i * 16 + q * 4;
    #pragma unroll
    for (int jn = 0; jn < FN; jn++) {
      int n = n0 + wn * (BN / 2) + jn * 16 + lr;
      float bv = bias ? bias[n] : 0.f;
      #pragma unroll
      for (int r2 = 0; r2 < 4; r2++) {
        size_t off = (size_t)(mbase + r2) * ldc + n;
        float o = acc[i][jn][r2] + bv;
        if (res) o += res[off];
        C[off] = o;
      }
    }
  }
}

// ---------------------------------------------------------------- depthwise causal conv(4) + silu
__global__ __launch_bounds__(256) void conv_silu_kernel(
    const float* __restrict__ xz, const float* __restrict__ cw,
    const float* __restrict__ cb, float* __restrict__ xc) {
  int i = blockIdx.x * 256 + threadIdx.x;
  int d = i % DI_;
  int tk = i / DI_;
  int t = tk & (L_ - 1);
  float acc = cb[d];
  #pragma unroll
  for (int k = 0; k < DC_; k++) {
    int tt = t - 3 + k;
    if (tt >= 0) acc += xz[(size_t)(tk - 3 + k) * (2 * DI_) + d] * cw[d * DC_ + k];
  }
  xc[i] = siluf_(acc);
}

// ---------------------------------------------------------------- xdbl = xc @ W_x  (N=80, K=1536)
// grid = NTOK/2 blocks; block 256 = 2 rows x 128 lanes (n<80 active in k-loop)
__global__ __launch_bounds__(256) void xdbl_kernel(
    const float* __restrict__ xc, const float* __restrict__ Wx, float* __restrict__ xdbl) {
  __shared__ float As[2 * DI_];                  // 12 KB: two xc rows (contiguous)
  int m0 = blockIdx.x * 2;
  const float4* src = (const float4*)(xc + (size_t)m0 * DI_);
  for (int i = threadIdx.x; i < 2 * DI_ / 4; i += 256) ((float4*)As)[i] = src[i];
  __syncthreads();
  int r = threadIdx.x >> 7, n = threadIdx.x & 127;
  if (n < 80) {
    const float* a = As + r * DI_;
    float acc = 0.f;
    #pragma unroll 8
    for (int k = 0; k < DI_; k++) acc += a[k] * Wx[k * 80 + n];
    xdbl[(size_t)(m0 + r) * 80 + n] = acc;
  }
}

// ---------------------------------------------------------------- dt = softplus(xdbl[:, :48] @ W_dt + b_dt)
// grid = (NTOK, DI/256); block 256; thread-per-output, Wdt is L2-resident (295 KB)
__global__ __launch_bounds__(256) void dt_kernel(
    const float* __restrict__ xdbl, const float* __restrict__ Wdt,
    const float* __restrict__ bdt, float* __restrict__ dt) {
  __shared__ float As[DR_];
  int m = blockIdx.x;
  int n = blockIdx.y * 256 + threadIdx.x;
  if (threadIdx.x < DR_) As[threadIdx.x] = xdbl[(size_t)m * 80 + threadIdx.x];
  __syncthreads();
  float acc = bdt[n];
  #pragma unroll
  for (int k = 0; k < DR_; k++) acc += As[k] * Wdt[k * DI_ + n];
  dt[(size_t)m * DI_ + n] = softplusf_(acc);
}

// ---------------------------------------------------------------- chunked selective scan
// Pass 1: per-chunk local scan summaries.
// grid = B * (DI/16) * NCH, block 256 = 16 channels x 16 states
__global__ __launch_bounds__(256) void scan1_kernel(
    const float* __restrict__ dt,
    const float* __restrict__ xc,
    const float* __restrict__ xdbl,
    const float* __restrict__ A_log,
    float* __restrict__ sumA, float* __restrict__ sumS) {
  __shared__ float dts[TCH][16], xs[TCH][16], Bs[TCH][16];
  int blk = blockIdx.x;
  int c = blk % NCH;
  int bd = blk / NCH;
  int b = bd / (DI_ / 16);
  int dbase = (bd % (DI_ / 16)) * 16;
  int tid = threadIdx.x;
  int ch = tid >> 4;
  int st = tid & 15;
  int d = dbase + ch;
  int tok0 = b * L_ + c * TCH;
  #pragma unroll
  for (int rep = 0; rep < TCH / 16; rep++) {
    int tt = rep * 16 + (tid >> 4);
    int cc = tid & 15;
    int tok = tok0 + tt;
    dts[tt][cc] = dt[(size_t)tok * DI_ + dbase + cc];
    xs [tt][cc] = xc[(size_t)tok * DI_ + dbase + cc];
    Bs [tt][cc] = xdbl[(size_t)tok * 80 + 48 + cc];
  }
  __syncthreads();
  float Av = -__expf(A_log[d * DS_ + st]);
  float s = 0.f, ap = 1.f;
  for (int tt = 0; tt < TCH; tt++) {
    float dtv = dts[tt][ch];
    float xv  = xs[tt][ch];
    float e = __expf(dtv * Av);
    s = s * e + dtv * xv * Bs[tt][st];
    ap *= e;
  }
  int idx = ((c * B_ + b) * DI_ + d) * DS_ + st;
  sumA[idx] = ap;
  sumS[idx] = s;
}

// Pass 2: combine chunk summaries -> carry-in per chunk. 49152 threads.
__global__ __launch_bounds__(256) void scan2_kernel(
    const float* __restrict__ sumA, const float* __restrict__ sumS,
    float* __restrict__ carry) {
  int i = blockIdx.x * 256 + threadIdx.x;
  const int stride = B_ * DI_ * DS_;
  float s = 0.f;
  #pragma unroll
  for (int c = 0; c < NCH; c++) {
    carry[c * stride + i] = s;
    s = sumS[c * stride + i] + sumA[c * stride + i] * s;
  }
}

// Pass 3: replay chunk with carry-in, compute y, emit bf16 hi/lo planes.
// grid = B * (DI/16) * NCH, block 256
__global__ __launch_bounds__(256) void scan3_kernel(
    const float* __restrict__ dt,
    const float* __restrict__ xc,
    const float* __restrict__ xdbl,
    const float* __restrict__ xz,
    const float* __restrict__ A_log,
    const float* __restrict__ Dp,
    const float* __restrict__ carry,
    u16* __restrict__ yh, u16* __restrict__ yl) {
  __shared__ float dts[TCH][16], xs[TCH][16], zs[TCH][16];
  __shared__ float Bs[TCH][16], Cs[TCH][16], ys[TCH][16];
  int blk = blockIdx.x;
  int c = blk % NCH;
  int bd = blk / NCH;
  int b = bd / (DI_ / 16);
  int dbase = (bd % (DI_ / 16)) * 16;
  int tid = threadIdx.x;
  int ch = tid >> 4;
  int st = tid & 15;
  int d = dbase + ch;
  int tok0 = b * L_ + c * TCH;
  #pragma unroll
  for (int rep = 0; rep < TCH / 16; rep++) {
    int tt = rep * 16 + (tid >> 4);
    int cc = tid & 15;
    int tok = tok0 + tt;
    dts[tt][cc] = dt[(size_t)tok * DI_ + dbase + cc];
    xs [tt][cc] = xc[(size_t)tok * DI_ + dbase + cc];
    zs [tt][cc] = xz[(size_t)tok * (2 * DI_) + DI_ + dbase + cc];
    Bs [tt][cc] = xdbl[(size_t)tok * 80 + 48 + cc];
    Cs [tt][cc] = xdbl[(size_t)tok * 80 + 64 + cc];
  }
  __syncthreads();
  float Av  = -__expf(A_log[d * DS_ + st]);
  float Dpd = Dp[d];
  float s = carry[((c * B_ + b) * DI_ + d) * DS_ + st];
  for (int tt = 0; tt < TCH; tt++) {
    float dtv = dts[tt][ch];
    float xv  = xs[tt][ch];
    float e = __expf(dtv * Av);
    s = s * e + dtv * xv * Bs[tt][st];
    float p = s * Cs[tt][st];
    p += __shfl_xor(p, 1, 64);
    p += __shfl_xor(p, 2, 64);
    p += __shfl_xor(p, 4, 64);
    p += __shfl_xor(p, 8, 64);
    if (st == 0) {
      float yv = p + Dpd * xv;
      float zv = zs[tt][ch];
      ys[tt][ch] = yv * siluf_(zv);
    }
  }
  __syncthreads();
  #pragma unroll
  for (int rep = 0; rep < TCH / 16; rep++) {
    int tt = rep * 16 + (tid >> 4);
    int cc = tid & 15;
    int tok = tok0 + tt;
    float v = ys[tt][cc];
    unsigned hb = f2bf(v);
    size_t idx = (size_t)tok * DI_ + dbase + cc;
    yh[idx] = (u16)hb;
    yl[idx] = (u16)f2bf(v - bf2f(hb));
  }
}

// ---------------------------------------------------------------- launcher
extern "C" void kernel_launch(void* const* d_in, const int* in_sizes, int n_in,
                              void* d_out, int out_size, void* d_ws, size_t ws_size,
                              hipStream_t stream) {
  const int*   ids     = (const int*)  d_in[0];
  const float* t_norm  = (const float*)d_in[1];
  const float* tok_emb = (const float*)d_in[2];
  const float* tw1     = (const float*)d_in[3];
  const float* tb1     = (const float*)d_in[4];
  const float* tw2     = (const float*)d_in[5];
  const float* tb2     = (const float*)d_in[6];
  const float* ln_g    = (const float*)d_in[7];
  const float* ln_b    = (const float*)d_in[8];
  const float* W_in    = (const float*)d_in[9];
  const float* b_in    = (const float*)d_in[10];
  const float* conv_w  = (const float*)d_in[11];
  const float* conv_b  = (const float*)d_in[12];
  const float* W_x     = (const float*)d_in[13];
  const float* W_dt    = (const float*)d_in[14];
  const float* b_dt    = (const float*)d_in[15];
  const float* A_log   = (const float*)d_in[16];
  const float* D_p     = (const float*)d_in[17];
  const float* W_out   = (const float*)d_in[18];
  const float* b_out   = (const float*)d_in[19];
  const float* fn_g    = (const float*)d_in[20];
  const float* fn_b    = (const float*)d_in[21];
  const float* W_head  = (const float*)d_in[22];
  const float* b_head  = (const float*)d_in[23];

  float* ws = (float*)d_ws;
  float* h    = ws; ws += (size_t)NTOK * D_;
  float* hn   = ws; ws += (size_t)NTOK * D_;
  float* temb = ws; ws += (size_t)B_ * D_;
  float* xz   = ws; ws += (size_t)NTOK * 2 * DI_;
  float* xc   = ws; ws += (size_t)NTOK * DI_;
  float* dtb  = ws; ws += (size_t)NTOK * DI_;
  float* xdbl = ws; ws += (size_t)NTOK * 80;
  u16* hnh = (u16*)ws; ws += (size_t)NTOK * D_ / 2;
  u16* hnl = (u16*)ws; ws += (size_t)NTOK * D_ / 2;
  u16* yh  = (u16*)ws; ws += (size_t)NTOK * DI_ / 2;
  u16* yl  = (u16*)ws; ws += (size_t)NTOK * DI_ / 2;
  u16* wbh = (u16*)ws; ws += (size_t)6400 * 768 / 2;   // weight split buffer (reused)
  u16* wbl = (u16*)ws; ws += (size_t)6400 * 768 / 2;
  float* sumA  = ws; ws += (size_t)NCH * B_ * DI_ * DS_;
  float* sumS  = ws; ws += (size_t)NCH * B_ * DI_ * DS_;
  float* carry = ws; ws += (size_t)NCH * B_ * DI_ * DS_;

  embed_kernel<<<NTOK, 192, 0, stream>>>(ids, tok_emb, h);
  temb_kernel<<<B_ * 3, 256, 0, stream>>>(t_norm, tw1, tb1, tw2, tb2, temb);

  for (int l = 0; l < NL_; l++) {
    // W_in [768][3072] -> [3072][768] split planes
    wsplit_kernel<<<dim3(3072 / 64, 768 / 64), 256, 0, stream>>>(
        W_in + (size_t)l * D_ * 2 * DI_, 3072, 0, 768, wbh, wbl);
    ln_kernel<<<NTOK, 256, 0, stream>>>(h, temb, ln_g + l * D_, ln_b + l * D_, hn, hnh, hnl);
    // xz = hn @ W_in + b_in   (M=1024, N=3072, K=768)
    gemm3<128, 64><<<dim3(NTOK / 128, 3072 / 64), 256, 0, stream>>>(
        768, 3072, hnh, hnl, wbh, wbl, b_in + (size_t)l * 2 * DI_, nullptr, xz);
    conv_silu_kernel<<<(NTOK * DI_) / 256, 256, 0, stream>>>(
        xz, conv_w + (size_t)l * DI_ * DC_, conv_b + (size_t)l * DI_, xc);
    xdbl_kernel<<<NTOK / 2, 256, 0, stream>>>(xc, W_x + (size_t)l * DI_ * 80, xdbl);
    dt_kernel<<<dim3(NTOK, DI_ / 256), 256, 0, stream>>>(
        xdbl, W_dt + (size_t)l * DR_ * DI_, b_dt + (size_t)l * DI_, dtb);
    // chunked scan: local summaries -> carry combine -> replay+output
    scan1_kernel<<<B_ * (DI_ / 16) * NCH, 256, 0, stream>>>(
        dtb, xc, xdbl, A_log + (size_t)l * DI_ * DS_, sumA, sumS);
    scan2_kernel<<<(B_ * DI_ * DS_) / 256, 256, 0, stream>>>(sumA, sumS, carry);
    scan3_kernel<<<B_ * (DI_ / 16) * NCH, 256, 0, stream>>>(
        dtb, xc, xdbl, xz, A_log + (size_t)l * DI_ * DS_, D_p + (size_t)l * DI_, carry, yh, yl);
    // W_out [1536][768] -> [768][1536] split planes
    wsplit_kernel<<<dim3(768 / 64, 1536 / 64), 256, 0, stream>>>(
        W_out + (size_t)l * DI_ * D_, 768, 0, 1536, wbh, wbl);
    // h = hn + y @ W_out + b_out   (M=1024, N=768, K=1536; res = hn)
    gemm3<64, 64><<<dim3(NTOK / 64, D_ / 64), 256, 0, stream>>>(
        1536, 768, yh, yl, wbh, wbl, b_out + (size_t)l * D_, hn, h);
  }

  ln_kernel<<<NTOK, 256, 0, stream>>>(h, nullptr, fn_g, fn_b, hn, hnh, hnl);
  // head in 5 chunks of 6400 columns: split W_head slice, then GEMM
  for (int c = 0; c < 5; c++) {
    int c0 = c * 6400;
    wsplit_kernel<<<dim3(6400 / 64, 768 / 64), 256, 0, stream>>>(
        W_head, V_SZ, c0, 768, wbh, wbl);
    gemm3<128, 64><<<dim3(NTOK / 128, 6400 / 64), 256, 0, stream>>>(
        768, V_SZ, hnh, hnl, wbh, wbl, b_head + c0, nullptr, (float*)d_out + c0);
  }
}